// Round 1
// baseline (368.429 us; speedup 1.0000x reference)
//
#include <hip/hip_runtime.h>

#define NROWS 4096
#define DIM   512
#define MARGIN 0.2f
#define EPS 1e-6f
#define BIG 1e9f

// monotone float <-> uint mapping (order-preserving), for atomicMax/Min on floats
__device__ __forceinline__ unsigned enc_f(float x) {
    unsigned u = __float_as_uint(x);
    return (u & 0x80000000u) ? ~u : (u | 0x80000000u);
}
__device__ __forceinline__ float dec_f(unsigned u) {
    return (u & 0x80000000u) ? __uint_as_float(u ^ 0x80000000u) : __uint_as_float(~u);
}

__global__ void init_kernel(unsigned* __restrict__ hp, unsigned* __restrict__ hn) {
    int i = blockIdx.x * blockDim.x + threadIdx.x;
    if (i < NROWS) {
        hp[i] = enc_f(-BIG);  // hardest positive: running max
        hn[i] = enc_f(BIG);   // hardest negative: running min
    }
}

// Fused Gram-matrix + batch-hard mining.
// Grid: (16 col-chunks, 64 row-groups). Block: 256 threads.
// Each block: rows [r0, r0+64), cols [c0, c0+256) in 4 tiles of 64.
// Thread (tx,ty) owns rows {ty+16i}, cols {tx+16j}  (strided to keep
// ds_read_b128 fragment addresses 4 banks apart -> conflict-free).
__launch_bounds__(256, 2)
__global__ void dist_mine_kernel(const float* __restrict__ feats,
                                 const int* __restrict__ labels,
                                 unsigned* __restrict__ hp,
                                 unsigned* __restrict__ hn) {
    __shared__ float As[64][68];  // [row][k], pad 68 floats (16B-aligned rows)
    __shared__ float Bs[64][68];

    const int tid = threadIdx.x;
    const int tx = tid & 15;      // column-thread 0..15
    const int ty = tid >> 4;      // row-thread 0..15
    const int r0 = blockIdx.y * 64;
    const int c0 = blockIdx.x * 256;

    // staging indices: thread loads 4 float4 per tile per matrix
    const int srow  = tid >> 4;         // 0..15
    const int scol4 = (tid & 15) * 4;   // 0,4,..,60

    int rlab[4];
#pragma unroll
    for (int i = 0; i < 4; i++) rlab[i] = labels[r0 + ty + 16 * i];

    float pmax[4] = {-BIG, -BIG, -BIG, -BIG};
    float nmin[4] = {BIG, BIG, BIG, BIG};

    for (int ct = 0; ct < 4; ++ct) {
        const int c = c0 + ct * 64;
        int clab[4];
#pragma unroll
        for (int j = 0; j < 4; j++) clab[j] = labels[c + tx + 16 * j];

        float acc[4][4];
#pragma unroll
        for (int i = 0; i < 4; i++)
#pragma unroll
            for (int j = 0; j < 4; j++) acc[i][j] = 0.0f;

        for (int kt = 0; kt < 8; ++kt) {
            const int kbase = kt * 64;
            // stage 64x64 A tile and B tile (coalesced float4 global loads)
#pragma unroll
            for (int p = 0; p < 4; p++) {
                const int row = srow + p * 16;
                const float4 av = *(const float4*)&feats[(size_t)(r0 + row) * DIM + kbase + scol4];
                *(float4*)&As[row][scol4] = av;
                const float4 bv = *(const float4*)&feats[(size_t)(c + row) * DIM + kbase + scol4];
                *(float4*)&Bs[row][scol4] = bv;
            }
            __syncthreads();

#pragma unroll
            for (int kk = 0; kk < 64; kk += 4) {
                float4 a[4], b[4];
#pragma unroll
                for (int i = 0; i < 4; i++) a[i] = *(const float4*)&As[ty + 16 * i][kk];
#pragma unroll
                for (int j = 0; j < 4; j++) b[j] = *(const float4*)&Bs[tx + 16 * j][kk];
#pragma unroll
                for (int i = 0; i < 4; i++)
#pragma unroll
                    for (int j = 0; j < 4; j++) {
                        acc[i][j] = fmaf(a[i].x, b[j].x, acc[i][j]);
                        acc[i][j] = fmaf(a[i].y, b[j].y, acc[i][j]);
                        acc[i][j] = fmaf(a[i].z, b[j].z, acc[i][j]);
                        acc[i][j] = fmaf(a[i].w, b[j].w, acc[i][j]);
                    }
            }
            __syncthreads();
        }

        // fused batch-hard mining on this 64x64 tile
#pragma unroll
        for (int i = 0; i < 4; i++)
#pragma unroll
            for (int j = 0; j < 4; j++) {
                const float dist = 1.0f - acc[i][j];
                const bool same = (rlab[i] == clab[j]);
                if (same) {
                    if (dist > EPS) pmax[i] = fmaxf(pmax[i], dist);
                } else {
                    nmin[i] = fminf(nmin[i], dist);
                }
            }
    }

    // reduce across the 16 column-threads (same ty -> 16 consecutive lanes)
#pragma unroll
    for (int off = 8; off; off >>= 1) {
#pragma unroll
        for (int i = 0; i < 4; i++) {
            pmax[i] = fmaxf(pmax[i], __shfl_xor(pmax[i], off, 16));
            nmin[i] = fminf(nmin[i], __shfl_xor(nmin[i], off, 16));
        }
    }
    if (tx == 0) {
#pragma unroll
        for (int i = 0; i < 4; i++) {
            const int r = r0 + ty + 16 * i;
            atomicMax(&hp[r], enc_f(pmax[i]));
            atomicMin(&hn[r], enc_f(nmin[i]));
        }
    }
}

__global__ void finalize_kernel(const unsigned* __restrict__ hp,
                                const unsigned* __restrict__ hn,
                                float* __restrict__ out) {
    __shared__ float ssum[4];
    __shared__ int scnt[4];
    const int tid = threadIdx.x;
    float sum = 0.0f;
    int cnt = 0;
    for (int i = tid; i < NROWS; i += 256) {
        const float p = dec_f(hp[i]);
        const float n = dec_f(hn[i]);
        const float tl = p - n + MARGIN;
        if (tl > 0.0f) { sum += tl; cnt++; }
    }
#pragma unroll
    for (int off = 32; off; off >>= 1) {
        sum += __shfl_down(sum, off, 64);
        cnt += __shfl_down(cnt, off, 64);
    }
    const int w = tid >> 6, lane = tid & 63;
    if (lane == 0) { ssum[w] = sum; scnt[w] = cnt; }
    __syncthreads();
    if (tid == 0) {
        const float s = ssum[0] + ssum[1] + ssum[2] + ssum[3];
        const int c = scnt[0] + scnt[1] + scnt[2] + scnt[3];
        out[0] = (c > 0) ? s / (float)c : 0.0f;
    }
}

extern "C" void kernel_launch(void* const* d_in, const int* in_sizes, int n_in,
                              void* d_out, int out_size, void* d_ws, size_t ws_size,
                              hipStream_t stream) {
    const float* feats = (const float*)d_in[0];
    const int* labels = (const int*)d_in[1];
    float* out = (float*)d_out;

    unsigned* hp = (unsigned*)d_ws;           // 4096 u32
    unsigned* hn = hp + NROWS;                // 4096 u32

    init_kernel<<<16, 256, 0, stream>>>(hp, hn);
    dim3 grid(16, 64);
    dist_mine_kernel<<<grid, 256, 0, stream>>>(feats, labels, hp, hn);
    finalize_kernel<<<1, 256, 0, stream>>>(hp, hn, out);
}

// Round 2
// 135.175 us; speedup vs baseline: 2.7256x; 2.7256x over previous
//
#include <hip/hip_runtime.h>

#define NROWS 4096
#define DIM   512
#define MARGIN 0.2f
#define EPS 1e-6f
#define BIG 1e9f

typedef __attribute__((ext_vector_type(8))) short bf16x8;
typedef __attribute__((ext_vector_type(4))) float f32x4;

// monotone float <-> uint mapping (order-preserving), for atomicMax/Min on floats
__device__ __forceinline__ unsigned enc_f(float x) {
    unsigned u = __float_as_uint(x);
    return (u & 0x80000000u) ? ~u : (u | 0x80000000u);
}
__device__ __forceinline__ float dec_f(unsigned u) {
    return (u & 0x80000000u) ? __uint_as_float(u ^ 0x80000000u) : __uint_as_float(~u);
}

__device__ __forceinline__ unsigned short f2bf_rne(float x) {
    unsigned u = __float_as_uint(x);
    unsigned r = u + 0x7FFFu + ((u >> 16) & 1u);
    return (unsigned short)(r >> 16);
}

__global__ void init_kernel(unsigned* __restrict__ hp, unsigned* __restrict__ hn) {
    int i = blockIdx.x * blockDim.x + threadIdx.x;
    if (i < NROWS) {
        hp[i] = enc_f(-BIG);
        hn[i] = enc_f(BIG);
    }
}

// split f32 feats into bf16 hi + bf16 lo (hi = rne(x), lo = rne(x - hi))
__global__ void prep_kernel(const float* __restrict__ feats,
                            unsigned short* __restrict__ fhi,
                            unsigned short* __restrict__ flo) {
    const int i = (blockIdx.x * 256 + threadIdx.x) * 4;
    const float4 v = *(const float4*)&feats[i];
    float x[4] = {v.x, v.y, v.z, v.w};
    unsigned short h[4], l[4];
#pragma unroll
    for (int j = 0; j < 4; j++) {
        h[j] = f2bf_rne(x[j]);
        const float hf = __uint_as_float(((unsigned)h[j]) << 16);
        l[j] = f2bf_rne(x[j] - hf);
    }
    *(ushort4*)&fhi[i] = make_ushort4(h[0], h[1], h[2], h[3]);
    *(ushort4*)&flo[i] = make_ushort4(l[0], l[1], l[2], l[3]);
}

#define AS1(p) ((const __attribute__((address_space(1))) unsigned int*)(p))
#define AS3(p) ((__attribute__((address_space(3))) unsigned int*)(p))

__device__ __forceinline__ void gll16(const unsigned short* g, unsigned short* l) {
    __builtin_amdgcn_global_load_lds(AS1(g), AS3(l), 16, 0, 0);
}

// Fused bf16x3 Gram GEMM + batch-hard mining.
// Grid 32x32 (XCD-swizzled). Block 256 = 4 waves (2x2). Tile 128x128, K_STEP=32.
// LDS [2][128][32] bf16 per array: 64B row stride => exactly-even bank usage for
// both global_load_lds (linear) and ds_read_b128 frag reads.
__launch_bounds__(256, 2)
__global__ void gram_mine_kernel(const unsigned short* __restrict__ fhi,
                                 const unsigned short* __restrict__ flo,
                                 const int* __restrict__ labels,
                                 unsigned* __restrict__ hp,
                                 unsigned* __restrict__ hn) {
    __shared__ __align__(16) unsigned short As_hi[2][128][32];
    __shared__ __align__(16) unsigned short As_lo[2][128][32];
    __shared__ __align__(16) unsigned short Bs_hi[2][128][32];
    __shared__ __align__(16) unsigned short Bs_lo[2][128][32];

    const int tid = threadIdx.x;
    const int lane = tid & 63;
    const int w = tid >> 6;        // wave 0..3
    const int wm = w >> 1;         // wave row 0..1
    const int wn = w & 1;          // wave col 0..1

    // XCD-aware bijective swizzle of flat block id (1024 % 8 == 0)
    const int bid = blockIdx.y * 32 + blockIdx.x;
    const int swz = (bid & 7) * 128 + (bid >> 3);
    const int bx = swz & 31;
    const int by = swz >> 5;
    const int r0 = by * 128;
    const int c0 = bx * 128;

    // staging: wave w covers rows [32w, 32w+32) of the 128-row tile, 2 gll per array
    const int srow = lane >> 2;          // 0..15
    const int scol = (lane & 3) * 8;     // bf16 elems: 0,8,16,24

#define STAGE(buf, kt)                                                                  \
    {                                                                                   \
        const int k0 = (kt) * 32;                                                       \
        _Pragma("unroll")                                                               \
        for (int q = 0; q < 2; q++) {                                                   \
            const int rr = 32 * w + 16 * q + srow;                                      \
            unsigned short* da = &As_hi[buf][32 * w + 16 * q][0] + lane * 8;            \
            gll16(&fhi[(size_t)(r0 + rr) * DIM + k0 + scol], da);                       \
            unsigned short* db = &As_lo[buf][32 * w + 16 * q][0] + lane * 8;            \
            gll16(&flo[(size_t)(r0 + rr) * DIM + k0 + scol], db);                       \
            unsigned short* dc = &Bs_hi[buf][32 * w + 16 * q][0] + lane * 8;            \
            gll16(&fhi[(size_t)(c0 + rr) * DIM + k0 + scol], dc);                       \
            unsigned short* dd = &Bs_lo[buf][32 * w + 16 * q][0] + lane * 8;            \
            gll16(&flo[(size_t)(c0 + rr) * DIM + k0 + scol], dd);                       \
        }                                                                               \
    }

    f32x4 acc[4][4];
#pragma unroll
    for (int i = 0; i < 4; i++)
#pragma unroll
        for (int j = 0; j < 4; j++) acc[i][j] = (f32x4)(0.0f);

    const int frow = lane & 15;     // fragment row/col within 16
    const int fkg = lane >> 4;      // k-group 0..3 (8 bf16 each)

    STAGE(0, 0)

    for (int kt = 0; kt < 16; ++kt) {
        const int buf = kt & 1;
        __syncthreads();            // current buffer landed (drains vmcnt+lgkmcnt)
        if (kt < 15) STAGE(buf ^ 1, kt + 1)

        bf16x8 ah[4], al[4], bh[4], bl[4];
#pragma unroll
        for (int mi = 0; mi < 4; mi++) {
            const int r = wm * 64 + mi * 16 + frow;
            ah[mi] = *(const bf16x8*)&As_hi[buf][r][fkg * 8];
            al[mi] = *(const bf16x8*)&As_lo[buf][r][fkg * 8];
        }
#pragma unroll
        for (int nj = 0; nj < 4; nj++) {
            const int c = wn * 64 + nj * 16 + frow;
            bh[nj] = *(const bf16x8*)&Bs_hi[buf][c][fkg * 8];
            bl[nj] = *(const bf16x8*)&Bs_lo[buf][c][fkg * 8];
        }
        // 3 passes; each acc touched once per 16 mfma -> no dependent chains
#pragma unroll
        for (int mi = 0; mi < 4; mi++)
#pragma unroll
            for (int nj = 0; nj < 4; nj++)
                acc[mi][nj] = __builtin_amdgcn_mfma_f32_16x16x32_bf16(ah[mi], bh[nj], acc[mi][nj], 0, 0, 0);
#pragma unroll
        for (int mi = 0; mi < 4; mi++)
#pragma unroll
            for (int nj = 0; nj < 4; nj++)
                acc[mi][nj] = __builtin_amdgcn_mfma_f32_16x16x32_bf16(ah[mi], bl[nj], acc[mi][nj], 0, 0, 0);
#pragma unroll
        for (int mi = 0; mi < 4; mi++)
#pragma unroll
            for (int nj = 0; nj < 4; nj++)
                acc[mi][nj] = __builtin_amdgcn_mfma_f32_16x16x32_bf16(al[mi], bh[nj], acc[mi][nj], 0, 0, 0);
    }

    // ---- fused batch-hard mining epilogue ----
    // C frag layout: col = lane&15, row = (lane>>4)*4 + reg  [verified mapping]
    int rlab[4][4], clab[4];
#pragma unroll
    for (int mi = 0; mi < 4; mi++)
#pragma unroll
        for (int rg = 0; rg < 4; rg++)
            rlab[mi][rg] = labels[r0 + wm * 64 + mi * 16 + fkg * 4 + rg];
#pragma unroll
    for (int nj = 0; nj < 4; nj++)
        clab[nj] = labels[c0 + wn * 64 + nj * 16 + frow];

    float pmax[4][4], nmin[4][4];
#pragma unroll
    for (int mi = 0; mi < 4; mi++)
#pragma unroll
        for (int rg = 0; rg < 4; rg++) { pmax[mi][rg] = -BIG; nmin[mi][rg] = BIG; }

#pragma unroll
    for (int mi = 0; mi < 4; mi++)
#pragma unroll
        for (int nj = 0; nj < 4; nj++)
#pragma unroll
            for (int rg = 0; rg < 4; rg++) {
                const float dist = 1.0f - acc[mi][nj][rg];
                if (rlab[mi][rg] == clab[nj]) {
                    if (dist > EPS) pmax[mi][rg] = fmaxf(pmax[mi][rg], dist);
                } else {
                    nmin[mi][rg] = fminf(nmin[mi][rg], dist);
                }
            }

    // reduce across the 16 lanes holding the same rows (lane>>4 fixed)
#pragma unroll
    for (int off = 8; off; off >>= 1) {
#pragma unroll
        for (int mi = 0; mi < 4; mi++)
#pragma unroll
            for (int rg = 0; rg < 4; rg++) {
                pmax[mi][rg] = fmaxf(pmax[mi][rg], __shfl_xor(pmax[mi][rg], off, 16));
                nmin[mi][rg] = fminf(nmin[mi][rg], __shfl_xor(nmin[mi][rg], off, 16));
            }
    }
    if (frow == 0) {
#pragma unroll
        for (int mi = 0; mi < 4; mi++)
#pragma unroll
            for (int rg = 0; rg < 4; rg++) {
                const int R = r0 + wm * 64 + mi * 16 + fkg * 4 + rg;
                atomicMax(&hp[R], enc_f(pmax[mi][rg]));
                atomicMin(&hn[R], enc_f(nmin[mi][rg]));
            }
    }
#undef STAGE
}

// ---------------- fallback f32 path (used only if ws too small) ----------------
__launch_bounds__(256, 2)
__global__ void dist_mine_kernel(const float* __restrict__ feats,
                                 const int* __restrict__ labels,
                                 unsigned* __restrict__ hp,
                                 unsigned* __restrict__ hn) {
    __shared__ float As[64][68];
    __shared__ float Bs[64][68];
    const int tid = threadIdx.x;
    const int tx = tid & 15;
    const int ty = tid >> 4;
    const int r0 = blockIdx.y * 64;
    const int c0 = blockIdx.x * 256;
    const int srow = tid >> 4;
    const int scol4 = (tid & 15) * 4;
    int rlab[4];
#pragma unroll
    for (int i = 0; i < 4; i++) rlab[i] = labels[r0 + ty + 16 * i];
    float pmax[4] = {-BIG, -BIG, -BIG, -BIG};
    float nmin[4] = {BIG, BIG, BIG, BIG};
    for (int ct = 0; ct < 4; ++ct) {
        const int c = c0 + ct * 64;
        int clab[4];
#pragma unroll
        for (int j = 0; j < 4; j++) clab[j] = labels[c + tx + 16 * j];
        float acc[4][4];
#pragma unroll
        for (int i = 0; i < 4; i++)
#pragma unroll
            for (int j = 0; j < 4; j++) acc[i][j] = 0.0f;
        for (int kt = 0; kt < 8; ++kt) {
            const int kbase = kt * 64;
#pragma unroll
            for (int p = 0; p < 4; p++) {
                const int row = srow + p * 16;
                *(float4*)&As[row][scol4] = *(const float4*)&feats[(size_t)(r0 + row) * DIM + kbase + scol4];
                *(float4*)&Bs[row][scol4] = *(const float4*)&feats[(size_t)(c + row) * DIM + kbase + scol4];
            }
            __syncthreads();
#pragma unroll
            for (int kk = 0; kk < 64; kk += 4) {
                float4 a[4], b[4];
#pragma unroll
                for (int i = 0; i < 4; i++) a[i] = *(const float4*)&As[ty + 16 * i][kk];
#pragma unroll
                for (int j = 0; j < 4; j++) b[j] = *(const float4*)&Bs[tx + 16 * j][kk];
#pragma unroll
                for (int i = 0; i < 4; i++)
#pragma unroll
                    for (int j = 0; j < 4; j++) {
                        acc[i][j] = fmaf(a[i].x, b[j].x, acc[i][j]);
                        acc[i][j] = fmaf(a[i].y, b[j].y, acc[i][j]);
                        acc[i][j] = fmaf(a[i].z, b[j].z, acc[i][j]);
                        acc[i][j] = fmaf(a[i].w, b[j].w, acc[i][j]);
                    }
            }
            __syncthreads();
        }
#pragma unroll
        for (int i = 0; i < 4; i++)
#pragma unroll
            for (int j = 0; j < 4; j++) {
                const float dist = 1.0f - acc[i][j];
                if (rlab[i] == clab[j]) {
                    if (dist > EPS) pmax[i] = fmaxf(pmax[i], dist);
                } else {
                    nmin[i] = fminf(nmin[i], dist);
                }
            }
    }
#pragma unroll
    for (int off = 8; off; off >>= 1) {
#pragma unroll
        for (int i = 0; i < 4; i++) {
            pmax[i] = fmaxf(pmax[i], __shfl_xor(pmax[i], off, 16));
            nmin[i] = fminf(nmin[i], __shfl_xor(nmin[i], off, 16));
        }
    }
    if (tx == 0) {
#pragma unroll
        for (int i = 0; i < 4; i++) {
            const int r = r0 + ty + 16 * i;
            atomicMax(&hp[r], enc_f(pmax[i]));
            atomicMin(&hn[r], enc_f(nmin[i]));
        }
    }
}

__global__ void finalize_kernel(const unsigned* __restrict__ hp,
                                const unsigned* __restrict__ hn,
                                float* __restrict__ out) {
    __shared__ float ssum[4];
    __shared__ int scnt[4];
    const int tid = threadIdx.x;
    float sum = 0.0f;
    int cnt = 0;
    for (int i = tid; i < NROWS; i += 256) {
        const float p = dec_f(hp[i]);
        const float n = dec_f(hn[i]);
        const float tl = p - n + MARGIN;
        if (tl > 0.0f) { sum += tl; cnt++; }
    }
#pragma unroll
    for (int off = 32; off; off >>= 1) {
        sum += __shfl_down(sum, off, 64);
        cnt += __shfl_down(cnt, off, 64);
    }
    const int wv = tid >> 6, lane = tid & 63;
    if (lane == 0) { ssum[wv] = sum; scnt[wv] = cnt; }
    __syncthreads();
    if (tid == 0) {
        const float s = ssum[0] + ssum[1] + ssum[2] + ssum[3];
        const int c = scnt[0] + scnt[1] + scnt[2] + scnt[3];
        out[0] = (c > 0) ? s / (float)c : 0.0f;
    }
}

extern "C" void kernel_launch(void* const* d_in, const int* in_sizes, int n_in,
                              void* d_out, int out_size, void* d_ws, size_t ws_size,
                              hipStream_t stream) {
    const float* feats = (const float*)d_in[0];
    const int* labels = (const int*)d_in[1];
    float* out = (float*)d_out;

    unsigned* hp = (unsigned*)d_ws;               // 4096 u32
    unsigned* hn = hp + NROWS;                    // 4096 u32
    unsigned short* fhi = (unsigned short*)((char*)d_ws + 32768);
    unsigned short* flo = fhi + (size_t)NROWS * DIM;

    const size_t need = 32768 + (size_t)NROWS * DIM * 2 * 2;

    init_kernel<<<16, 256, 0, stream>>>(hp, hn);
    if (ws_size >= need) {
        prep_kernel<<<(NROWS * DIM) / (256 * 4), 256, 0, stream>>>(feats, fhi, flo);
        dim3 grid(32, 32);
        gram_mine_kernel<<<grid, 256, 0, stream>>>(fhi, flo, labels, hp, hn);
    } else {
        dim3 grid(16, 64);
        dist_mine_kernel<<<grid, 256, 0, stream>>>(feats, labels, hp, hn);
    }
    finalize_kernel<<<1, 256, 0, stream>>>(hp, hn, out);
}

// Round 3
// 125.650 us; speedup vs baseline: 2.9322x; 1.0758x over previous
//
#include <hip/hip_runtime.h>

#define NROWS 4096
#define DIM   512
#define MARGIN 0.2f
#define EPS 1e-6f
#define BIG 1e9f

typedef __attribute__((ext_vector_type(8))) short bf16x8;
typedef __attribute__((ext_vector_type(4))) float f32x4;

// monotone float <-> uint mapping (order-preserving), for atomicMax/Min on floats
__device__ __forceinline__ unsigned enc_f(float x) {
    unsigned u = __float_as_uint(x);
    return (u & 0x80000000u) ? ~u : (u | 0x80000000u);
}
__device__ __forceinline__ float dec_f(unsigned u) {
    return (u & 0x80000000u) ? __uint_as_float(u ^ 0x80000000u) : __uint_as_float(~u);
}

__device__ __forceinline__ unsigned short f2bf_rne(float x) {
    unsigned u = __float_as_uint(x);
    unsigned r = u + 0x7FFFu + ((u >> 16) & 1u);
    return (unsigned short)(r >> 16);
}

// split f32 feats into bf16 hi + lo; blocks 0..15 also init hp/hn (fused init)
__global__ void prep_kernel(const float* __restrict__ feats,
                            unsigned short* __restrict__ fhi,
                            unsigned short* __restrict__ flo,
                            unsigned* __restrict__ hp,
                            unsigned* __restrict__ hn) {
    const int gid = blockIdx.x * 256 + threadIdx.x;
    if (gid < NROWS) {
        hp[gid] = enc_f(-BIG);
        hn[gid] = enc_f(BIG);
    }
    const int i = gid * 4;
    const float4 v = *(const float4*)&feats[i];
    float x[4] = {v.x, v.y, v.z, v.w};
    unsigned short h[4], l[4];
#pragma unroll
    for (int j = 0; j < 4; j++) {
        h[j] = f2bf_rne(x[j]);
        const float hf = __uint_as_float(((unsigned)h[j]) << 16);
        l[j] = f2bf_rne(x[j] - hf);
    }
    *(ushort4*)&fhi[i] = make_ushort4(h[0], h[1], h[2], h[3]);
    *(ushort4*)&flo[i] = make_ushort4(l[0], l[1], l[2], l[3]);
}

#define AS1(p) ((const __attribute__((address_space(1))) unsigned int*)(p))
#define AS3(p) ((__attribute__((address_space(3))) unsigned int*)(p))

__device__ __forceinline__ void gll16(const unsigned short* g, unsigned short* l) {
    __builtin_amdgcn_global_load_lds(AS1(g), AS3(l), 16, 0, 0);
}

// Fused bf16x3 Gram GEMM + batch-hard mining, lower-triangle blocks only.
// Grid 528 (XCD-swizzled, 528%8==0). Block 256 = 4 waves (2x2). Tile 128x128,
// K_STEP=32. LDS linear for global_load_lds; 16B-chunk XOR swizzle
// (chunk ^= (row>>1)&3) applied on the GLOBAL source and on frag reads ->
// each 16-lane quarter's b128 reads cover all 32 banks exactly 2x.
__launch_bounds__(256, 2)
__global__ void gram_mine_kernel(const unsigned short* __restrict__ fhi,
                                 const unsigned short* __restrict__ flo,
                                 const int* __restrict__ labels,
                                 unsigned* __restrict__ hp,
                                 unsigned* __restrict__ hn) {
    __shared__ __align__(16) unsigned short As_hi[2][128][32];
    __shared__ __align__(16) unsigned short As_lo[2][128][32];
    __shared__ __align__(16) unsigned short Bs_hi[2][128][32];
    __shared__ __align__(16) unsigned short Bs_lo[2][128][32];

    const int tid = threadIdx.x;
    const int lane = tid & 63;
    const int w = tid >> 6;        // wave 0..3
    const int wm = w >> 1;         // wave row 0..1
    const int wn = w & 1;          // wave col 0..1

    // XCD-aware bijective swizzle (528 = 8 * 66), then triangle unrank
    const int bid = blockIdx.x;
    const int t = (bid & 7) * 66 + (bid >> 3);
    int by = (int)((sqrtf(8.0f * (float)t + 1.0f) - 1.0f) * 0.5f);
    while ((by + 1) * (by + 2) / 2 <= t) by++;
    while (by * (by + 1) / 2 > t) by--;
    const int bx = t - by * (by + 1) / 2;      // bx <= by
    const int r0 = by * 128;
    const int c0 = bx * 128;
    const bool offdiag = (by != bx);

    // staging: lane l -> LDS row (l>>2) of 16-row group, 16B slot (l&3) [linear].
    // source chunk pre-swizzled so slot s of row r holds global chunk s^((r>>1)&3).
    const int srow = lane >> 2;                                   // 0..15
    const int scol = ((lane & 3) ^ ((lane >> 3) & 3)) * 8;        // swizzled src chunk

#define STAGE(buf, kt)                                                                  \
    {                                                                                   \
        const int k0 = (kt) * 32;                                                       \
        _Pragma("unroll")                                                               \
        for (int q = 0; q < 2; q++) {                                                   \
            const int rr = 32 * w + 16 * q + srow;                                      \
            unsigned short* da = &As_hi[buf][32 * w + 16 * q][0] + lane * 8;            \
            gll16(&fhi[(size_t)(r0 + rr) * DIM + k0 + scol], da);                       \
            unsigned short* db = &As_lo[buf][32 * w + 16 * q][0] + lane * 8;            \
            gll16(&flo[(size_t)(r0 + rr) * DIM + k0 + scol], db);                       \
            unsigned short* dc = &Bs_hi[buf][32 * w + 16 * q][0] + lane * 8;            \
            gll16(&fhi[(size_t)(c0 + rr) * DIM + k0 + scol], dc);                       \
            unsigned short* dd = &Bs_lo[buf][32 * w + 16 * q][0] + lane * 8;            \
            gll16(&flo[(size_t)(c0 + rr) * DIM + k0 + scol], dd);                       \
        }                                                                               \
    }

    f32x4 acc[4][4];
#pragma unroll
    for (int i = 0; i < 4; i++)
#pragma unroll
        for (int j = 0; j < 4; j++) acc[i][j] = (f32x4)(0.0f);

    const int frow = lane & 15;     // fragment row/col within 16
    const int fkg = lane >> 4;      // k-group 0..3 (8 bf16 each)

    STAGE(0, 0)

    for (int kt = 0; kt < 16; ++kt) {
        const int buf = kt & 1;
        __syncthreads();            // current buffer landed (drains vmcnt+lgkmcnt)
        if (kt < 15) STAGE(buf ^ 1, kt + 1)

        bf16x8 ah[4], al[4], bh[4], bl[4];
#pragma unroll
        for (int mi = 0; mi < 4; mi++) {
            const int r = wm * 64 + mi * 16 + frow;
            const int ch = (fkg ^ ((r >> 1) & 3)) * 8;
            ah[mi] = *(const bf16x8*)&As_hi[buf][r][ch];
            al[mi] = *(const bf16x8*)&As_lo[buf][r][ch];
        }
#pragma unroll
        for (int nj = 0; nj < 4; nj++) {
            const int c = wn * 64 + nj * 16 + frow;
            const int ch = (fkg ^ ((c >> 1) & 3)) * 8;
            bh[nj] = *(const bf16x8*)&Bs_hi[buf][c][ch];
            bl[nj] = *(const bf16x8*)&Bs_lo[buf][c][ch];
        }
        // 3 passes; each acc touched once per 16 mfma -> no dependent chains
#pragma unroll
        for (int mi = 0; mi < 4; mi++)
#pragma unroll
            for (int nj = 0; nj < 4; nj++)
                acc[mi][nj] = __builtin_amdgcn_mfma_f32_16x16x32_bf16(ah[mi], bh[nj], acc[mi][nj], 0, 0, 0);
#pragma unroll
        for (int mi = 0; mi < 4; mi++)
#pragma unroll
            for (int nj = 0; nj < 4; nj++)
                acc[mi][nj] = __builtin_amdgcn_mfma_f32_16x16x32_bf16(ah[mi], bl[nj], acc[mi][nj], 0, 0, 0);
#pragma unroll
        for (int mi = 0; mi < 4; mi++)
#pragma unroll
            for (int nj = 0; nj < 4; nj++)
                acc[mi][nj] = __builtin_amdgcn_mfma_f32_16x16x32_bf16(al[mi], bh[nj], acc[mi][nj], 0, 0, 0);
    }

    // ---- fused batch-hard mining epilogue ----
    // C frag layout (16x16x32 bf16): col = lane&15 (frow), row = fkg*4 + reg
    int rlab[4][4], clab[4];
#pragma unroll
    for (int mi = 0; mi < 4; mi++)
#pragma unroll
        for (int rg = 0; rg < 4; rg++)
            rlab[mi][rg] = labels[r0 + wm * 64 + mi * 16 + fkg * 4 + rg];
#pragma unroll
    for (int nj = 0; nj < 4; nj++)
        clab[nj] = labels[c0 + wn * 64 + nj * 16 + frow];

    float pmax[4][4], nmin[4][4];   // row-anchor [mi][rg]
    float cpmax[4], cnmin[4];       // col-anchor [nj]
#pragma unroll
    for (int mi = 0; mi < 4; mi++)
#pragma unroll
        for (int rg = 0; rg < 4; rg++) { pmax[mi][rg] = -BIG; nmin[mi][rg] = BIG; }
#pragma unroll
    for (int nj = 0; nj < 4; nj++) { cpmax[nj] = -BIG; cnmin[nj] = BIG; }

#pragma unroll
    for (int mi = 0; mi < 4; mi++)
#pragma unroll
        for (int nj = 0; nj < 4; nj++)
#pragma unroll
            for (int rg = 0; rg < 4; rg++) {
                const float dist = 1.0f - acc[mi][nj][rg];
                if (rlab[mi][rg] == clab[nj]) {
                    if (dist > EPS) {
                        pmax[mi][rg] = fmaxf(pmax[mi][rg], dist);
                        cpmax[nj] = fmaxf(cpmax[nj], dist);
                    }
                } else {
                    nmin[mi][rg] = fminf(nmin[mi][rg], dist);
                    cnmin[nj] = fminf(cnmin[nj], dist);
                }
            }

    // row-anchor reduce across the 16 cols (lanes same fkg)
#pragma unroll
    for (int off = 8; off; off >>= 1) {
#pragma unroll
        for (int mi = 0; mi < 4; mi++)
#pragma unroll
            for (int rg = 0; rg < 4; rg++) {
                pmax[mi][rg] = fmaxf(pmax[mi][rg], __shfl_xor(pmax[mi][rg], off, 16));
                nmin[mi][rg] = fminf(nmin[mi][rg], __shfl_xor(nmin[mi][rg], off, 16));
            }
    }
    if (frow == 0) {
#pragma unroll
        for (int mi = 0; mi < 4; mi++)
#pragma unroll
            for (int rg = 0; rg < 4; rg++) {
                const int R = r0 + wm * 64 + mi * 16 + fkg * 4 + rg;
                atomicMax(&hp[R], enc_f(pmax[mi][rg]));
                atomicMin(&hn[R], enc_f(nmin[mi][rg]));
            }
    }

    // col-anchor (symmetric tile) reduce across the 16 rows (lanes same frow,
    // fkg varies: xor 16, 32 over full wave). Skip on diagonal (duplicate).
    if (offdiag) {
#pragma unroll
        for (int nj = 0; nj < 4; nj++) {
            cpmax[nj] = fmaxf(cpmax[nj], __shfl_xor(cpmax[nj], 16, 64));
            cpmax[nj] = fmaxf(cpmax[nj], __shfl_xor(cpmax[nj], 32, 64));
            cnmin[nj] = fminf(cnmin[nj], __shfl_xor(cnmin[nj], 16, 64));
            cnmin[nj] = fminf(cnmin[nj], __shfl_xor(cnmin[nj], 32, 64));
        }
        if (fkg == 0) {
#pragma unroll
            for (int nj = 0; nj < 4; nj++) {
                const int C = c0 + wn * 64 + nj * 16 + frow;
                atomicMax(&hp[C], enc_f(cpmax[nj]));
                atomicMin(&hn[C], enc_f(cnmin[nj]));
            }
        }
    }
#undef STAGE
}

__global__ void finalize_kernel(const unsigned* __restrict__ hp,
                                const unsigned* __restrict__ hn,
                                float* __restrict__ out) {
    __shared__ float ssum[4];
    __shared__ int scnt[4];
    const int tid = threadIdx.x;
    float sum = 0.0f;
    int cnt = 0;
    for (int i = tid; i < NROWS; i += 256) {
        const float p = dec_f(hp[i]);
        const float n = dec_f(hn[i]);
        const float tl = p - n + MARGIN;
        if (tl > 0.0f) { sum += tl; cnt++; }
    }
#pragma unroll
    for (int off = 32; off; off >>= 1) {
        sum += __shfl_down(sum, off, 64);
        cnt += __shfl_down(cnt, off, 64);
    }
    const int wv = tid >> 6, lane = tid & 63;
    if (lane == 0) { ssum[wv] = sum; scnt[wv] = cnt; }
    __syncthreads();
    if (tid == 0) {
        const float s = ssum[0] + ssum[1] + ssum[2] + ssum[3];
        const int c = scnt[0] + scnt[1] + scnt[2] + scnt[3];
        out[0] = (c > 0) ? s / (float)c : 0.0f;
    }
}

// ---------------- fallback f32 path (used only if ws too small) ----------------
__global__ void init_kernel(unsigned* __restrict__ hp, unsigned* __restrict__ hn) {
    int i = blockIdx.x * blockDim.x + threadIdx.x;
    if (i < NROWS) {
        hp[i] = enc_f(-BIG);
        hn[i] = enc_f(BIG);
    }
}

__launch_bounds__(256, 2)
__global__ void dist_mine_kernel(const float* __restrict__ feats,
                                 const int* __restrict__ labels,
                                 unsigned* __restrict__ hp,
                                 unsigned* __restrict__ hn) {
    __shared__ float As[64][68];
    __shared__ float Bs[64][68];
    const int tid = threadIdx.x;
    const int tx = tid & 15;
    const int ty = tid >> 4;
    const int r0 = blockIdx.y * 64;
    const int c0 = blockIdx.x * 256;
    const int srow = tid >> 4;
    const int scol4 = (tid & 15) * 4;
    int rlab[4];
#pragma unroll
    for (int i = 0; i < 4; i++) rlab[i] = labels[r0 + ty + 16 * i];
    float pmax[4] = {-BIG, -BIG, -BIG, -BIG};
    float nmin[4] = {BIG, BIG, BIG, BIG};
    for (int ct = 0; ct < 4; ++ct) {
        const int c = c0 + ct * 64;
        int clab[4];
#pragma unroll
        for (int j = 0; j < 4; j++) clab[j] = labels[c + tx + 16 * j];
        float acc[4][4];
#pragma unroll
        for (int i = 0; i < 4; i++)
#pragma unroll
            for (int j = 0; j < 4; j++) acc[i][j] = 0.0f;
        for (int kt = 0; kt < 8; ++kt) {
            const int kbase = kt * 64;
#pragma unroll
            for (int p = 0; p < 4; p++) {
                const int row = srow + p * 16;
                *(float4*)&As[row][scol4] = *(const float4*)&feats[(size_t)(r0 + row) * DIM + kbase + scol4];
                *(float4*)&Bs[row][scol4] = *(const float4*)&feats[(size_t)(c + row) * DIM + kbase + scol4];
            }
            __syncthreads();
#pragma unroll
            for (int kk = 0; kk < 64; kk += 4) {
                float4 a[4], b[4];
#pragma unroll
                for (int i = 0; i < 4; i++) a[i] = *(const float4*)&As[ty + 16 * i][kk];
#pragma unroll
                for (int j = 0; j < 4; j++) b[j] = *(const float4*)&Bs[tx + 16 * j][kk];
#pragma unroll
                for (int i = 0; i < 4; i++)
#pragma unroll
                    for (int j = 0; j < 4; j++) {
                        acc[i][j] = fmaf(a[i].x, b[j].x, acc[i][j]);
                        acc[i][j] = fmaf(a[i].y, b[j].y, acc[i][j]);
                        acc[i][j] = fmaf(a[i].z, b[j].z, acc[i][j]);
                        acc[i][j] = fmaf(a[i].w, b[j].w, acc[i][j]);
                    }
            }
            __syncthreads();
        }
#pragma unroll
        for (int i = 0; i < 4; i++)
#pragma unroll
            for (int j = 0; j < 4; j++) {
                const float dist = 1.0f - acc[i][j];
                if (rlab[i] == clab[j]) {
                    if (dist > EPS) pmax[i] = fmaxf(pmax[i], dist);
                } else {
                    nmin[i] = fminf(nmin[i], dist);
                }
            }
    }
#pragma unroll
    for (int off = 8; off; off >>= 1) {
#pragma unroll
        for (int i = 0; i < 4; i++) {
            pmax[i] = fmaxf(pmax[i], __shfl_xor(pmax[i], off, 16));
            nmin[i] = fminf(nmin[i], __shfl_xor(nmin[i], off, 16));
        }
    }
    if (tx == 0) {
#pragma unroll
        for (int i = 0; i < 4; i++) {
            const int r = r0 + ty + 16 * i;
            atomicMax(&hp[r], enc_f(pmax[i]));
            atomicMin(&hn[r], enc_f(nmin[i]));
        }
    }
}

extern "C" void kernel_launch(void* const* d_in, const int* in_sizes, int n_in,
                              void* d_out, int out_size, void* d_ws, size_t ws_size,
                              hipStream_t stream) {
    const float* feats = (const float*)d_in[0];
    const int* labels = (const int*)d_in[1];
    float* out = (float*)d_out;

    unsigned* hp = (unsigned*)d_ws;               // 4096 u32
    unsigned* hn = hp + NROWS;                    // 4096 u32
    unsigned short* fhi = (unsigned short*)((char*)d_ws + 32768);
    unsigned short* flo = fhi + (size_t)NROWS * DIM;

    const size_t need = 32768 + (size_t)NROWS * DIM * 2 * 2;

    if (ws_size >= need) {
        prep_kernel<<<(NROWS * DIM) / (256 * 4), 256, 0, stream>>>(feats, fhi, flo, hp, hn);
        gram_mine_kernel<<<528, 256, 0, stream>>>(fhi, flo, labels, hp, hn);
    } else {
        init_kernel<<<16, 256, 0, stream>>>(hp, hn);
        dim3 grid(16, 64);
        dist_mine_kernel<<<grid, 256, 0, stream>>>(feats, labels, hp, hn);
    }
    finalize_kernel<<<1, 256, 0, stream>>>(hp, hn, out);
}